// Round 2
// baseline (2387.492 us; speedup 1.0000x reference)
//
#include <hip/hip_runtime.h>
#include <hip/hip_bf16.h>

// ---------------- problem constants ----------------
#define CC 192
#define NHEADS 6
#define HDIM 32
#define NTOK 49          // tokens per window
#define NWIN 2048        // 32 * 8 * 8
#define MTOK 100352      // NWIN * NTOK == B*H*W
#define HIDDEN 768

typedef __hip_bfloat16 bf16;

// ---------------- kernel 1: LN1 + roll(-3,-3) + window partition ----------
// one wave (64 lanes) per token; 4 tokens per 256-thread block
__global__ __launch_bounds__(256) void k_ln1_part(
    const float* __restrict__ x, const float* __restrict__ g,
    const float* __restrict__ bta, bf16* __restrict__ xw) {
  int wv = blockIdx.x * 4 + (threadIdx.x >> 6);
  int lane = threadIdx.x & 63;
  int w = wv / NTOK, n = wv - w * NTOK;
  int b = w >> 6, wrem = w & 63;
  int hi = wrem >> 3, wi = wrem & 7;
  int i = n / 7, j = n - i * 7;
  int hs = hi * 7 + i, ws = wi * 7 + j;
  int hsrc = hs + 3; if (hsrc >= 56) hsrc -= 56;
  int wsrc = ws + 3; if (wsrc >= 56) wsrc -= 56;
  const float* row = x + (size_t)((b * 56 + hsrc) * 56 + wsrc) * CC;
  float v0 = row[lane];
  float v1 = row[lane + 64];
  float v2 = row[lane + 128];
  float s = v0 + v1 + v2;
  for (int m = 32; m; m >>= 1) s += __shfl_xor(s, m, 64);
  float mu = s * (1.0f / 192.0f);
  float d0 = v0 - mu, d1 = v1 - mu, d2 = v2 - mu;
  float q = d0 * d0 + d1 * d1 + d2 * d2;
  for (int m = 32; m; m >>= 1) q += __shfl_xor(q, m, 64);
  float inv = rsqrtf(q * (1.0f / 192.0f) + 1e-5f);
  bf16* orow = xw + (size_t)wv * CC;
  orow[lane]       = __float2bfloat16(d0 * inv * g[lane]       + bta[lane]);
  orow[lane + 64]  = __float2bfloat16(d1 * inv * g[lane + 64]  + bta[lane + 64]);
  orow[lane + 128] = __float2bfloat16(d2 * inv * g[lane + 128] + bta[lane + 128]);
}

// ---------------- kernel 5: LN2 (fp32 in, bf16 out, row-major) ----------
__global__ __launch_bounds__(256) void k_ln2(
    const float* __restrict__ x1, const float* __restrict__ g,
    const float* __restrict__ bta, bf16* __restrict__ xn2) {
  int wv = blockIdx.x * 4 + (threadIdx.x >> 6);
  int lane = threadIdx.x & 63;
  const float* row = x1 + (size_t)wv * CC;
  float v0 = row[lane], v1 = row[lane + 64], v2 = row[lane + 128];
  float s = v0 + v1 + v2;
  for (int m = 32; m; m >>= 1) s += __shfl_xor(s, m, 64);
  float mu = s * (1.0f / 192.0f);
  float d0 = v0 - mu, d1 = v1 - mu, d2 = v2 - mu;
  float q = d0 * d0 + d1 * d1 + d2 * d2;
  for (int m = 32; m; m >>= 1) q += __shfl_xor(q, m, 64);
  float inv = rsqrtf(q * (1.0f / 192.0f) + 1e-5f);
  bf16* orow = xn2 + (size_t)wv * CC;
  orow[lane]       = __float2bfloat16(d0 * inv * g[lane]       + bta[lane]);
  orow[lane + 64]  = __float2bfloat16(d1 * inv * g[lane + 64]  + bta[lane + 64]);
  orow[lane + 128] = __float2bfloat16(d2 * inv * g[lane + 128] + bta[lane + 128]);
}

// ---------------- generic tiled GEMM: out[m,n] = A[m,:] . Wt[n,:] + bias[n]
// A is bf16 activations; Wt/bias are fp32 weights from d_in.
// MODE 0: qkv scatter    MODE 1: proj + reverse/roll + residual (fp32 out)
// MODE 2: fc1 + GELU     MODE 3: fc2 + residual (fp32 out = d_out)
template <int MODE>
__global__ __launch_bounds__(256) void k_gemm(
    const bf16* __restrict__ A, const float* __restrict__ Wt,
    const float* __restrict__ bias, void* __restrict__ out0,
    const void* __restrict__ aux, int K) {
  __shared__ float As[64 * 17];
  __shared__ float Bs[64 * 17];
  int tx = threadIdx.x & 15, ty = threadIdx.x >> 4;
  int m0 = blockIdx.y * 64, n0 = blockIdx.x * 64;
  float acc[4][4] = {};
  for (int kt = 0; kt < K; kt += 16) {
    for (int e = threadIdx.x; e < 1024; e += 256) {
      int r = e >> 4, kk = e & 15;
      As[r * 17 + kk] = __bfloat162float(A[(size_t)(m0 + r) * K + kt + kk]);
      Bs[r * 17 + kk] = Wt[(size_t)(n0 + r) * K + kt + kk];
    }
    __syncthreads();
#pragma unroll
    for (int kk = 0; kk < 16; ++kk) {
      float a0 = As[(ty * 4 + 0) * 17 + kk];
      float a1 = As[(ty * 4 + 1) * 17 + kk];
      float a2 = As[(ty * 4 + 2) * 17 + kk];
      float a3 = As[(ty * 4 + 3) * 17 + kk];
      float b0 = Bs[(tx * 4 + 0) * 17 + kk];
      float b1 = Bs[(tx * 4 + 1) * 17 + kk];
      float b2 = Bs[(tx * 4 + 2) * 17 + kk];
      float b3 = Bs[(tx * 4 + 3) * 17 + kk];
      acc[0][0] += a0 * b0; acc[0][1] += a0 * b1; acc[0][2] += a0 * b2; acc[0][3] += a0 * b3;
      acc[1][0] += a1 * b0; acc[1][1] += a1 * b1; acc[1][2] += a1 * b2; acc[1][3] += a1 * b3;
      acc[2][0] += a2 * b0; acc[2][1] += a2 * b1; acc[2][2] += a2 * b2; acc[2][3] += a2 * b3;
      acc[3][0] += a3 * b0; acc[3][1] += a3 * b1; acc[3][2] += a3 * b2; acc[3][3] += a3 * b3;
    }
    __syncthreads();
  }
#pragma unroll
  for (int i = 0; i < 4; ++i) {
#pragma unroll
    for (int j = 0; j < 4; ++j) {
      int m = m0 + ty * 4 + i;
      int nn = n0 + tx * 4 + j;
      float v = acc[i][j] + bias[nn];
      if (MODE == 0) {  // qkv -> (s, win, head, tok, hd)
        int s = nn / 192;
        int rem = nn - s * 192;
        int hh = rem >> 5, d = rem & 31;
        int w = m / NTOK, r = m - w * NTOK;
        size_t off = (((size_t)s * NWIN + w) * NHEADS + hh) * (NTOK * HDIM) +
                     (size_t)r * HDIM + d;
        ((bf16*)out0)[off] = __float2bfloat16(v);
      } else if (MODE == 1) {  // proj + window-reverse + roll(+3) + residual
        int w = m / NTOK, r = m - w * NTOK;
        int b = w >> 6, wrem = w & 63;
        int hi = wrem >> 3, wi = wrem & 7;
        int ii = r / 7, jj = r - ii * 7;
        int hd = hi * 7 + ii + 3; if (hd >= 56) hd -= 56;
        int wd = wi * 7 + jj + 3; if (wd >= 56) wd -= 56;
        size_t off = (size_t)((b * 56 + hd) * 56 + wd) * CC + nn;
        float res = ((const float*)aux)[off];
        ((float*)out0)[off] = v + res;
      } else if (MODE == 2) {  // fc1 + exact GELU
        float ge = 0.5f * v * (1.0f + erff(v * 0.70710678118654752f));
        ((bf16*)out0)[(size_t)m * HIDDEN + nn] = __float2bfloat16(ge);
      } else {  // fc2 + residual (fp32 final output)
        float res = ((const float*)aux)[(size_t)m * CC + nn];
        ((float*)out0)[(size_t)m * CC + nn] = v + res;
      }
    }
  }
}

// ---------------- attention: one block per (window, head) ----------------
__global__ __launch_bounds__(256) void k_attn(
    const bf16* __restrict__ qkv, const float* __restrict__ table,
    const int* __restrict__ ridx, bf16* __restrict__ ao) {
  __shared__ float qs[49 * 33];
  __shared__ float ks[49 * 33];
  __shared__ float vs[49 * 33];
  __shared__ float S[49 * 50];
  int w = blockIdx.x / NHEADS, hh = blockIdx.x - w * NHEADS;
  size_t base = ((size_t)w * NHEADS + hh) * (NTOK * HDIM);
  const size_t SSTRIDE = (size_t)NWIN * NHEADS * NTOK * HDIM;  // 19,267,584
  const bf16* qp = qkv + base;
  const bf16* kp = qkv + SSTRIDE + base;
  const bf16* vp = qkv + 2 * SSTRIDE + base;
  for (int e = threadIdx.x; e < 1568; e += 256) {
    int r = e >> 5, d = e & 31;
    qs[r * 33 + d] = __bfloat162float(qp[e]);
    ks[r * 33 + d] = __bfloat162float(kp[e]);
    vs[r * 33 + d] = __bfloat162float(vp[e]);
  }
  __syncthreads();
  for (int e = threadIdx.x; e < 2401; e += 256) {
    int r = e / 49, c = e - r * 49;
    float acc = 0.0f;
#pragma unroll
    for (int kk = 0; kk < 32; ++kk) acc += qs[r * 33 + kk] * ks[c * 33 + kk];
    float bia = table[ridx[e] * NHEADS + hh];
    S[r * 50 + c] = acc * 0.17677669529663687f + bia;
  }
  __syncthreads();
  if (threadIdx.x < 49) {
    int r = threadIdx.x;
    float mx = -1e30f;
    for (int c = 0; c < 49; ++c) mx = fmaxf(mx, S[r * 50 + c]);
    float sum = 0.0f;
    for (int c = 0; c < 49; ++c) {
      float e2 = __expf(S[r * 50 + c] - mx);
      S[r * 50 + c] = e2;
      sum += e2;
    }
    float inv = 1.0f / sum;
    for (int c = 0; c < 49; ++c) S[r * 50 + c] *= inv;
  }
  __syncthreads();
  for (int e = threadIdx.x; e < 1568; e += 256) {
    int r = e >> 5, d = e & 31;
    float acc = 0.0f;
#pragma unroll
    for (int c = 0; c < 49; ++c) acc += S[r * 50 + c] * vs[c * 33 + d];
    ao[((size_t)w * NTOK + r) * CC + hh * HDIM + d] = __float2bfloat16(acc);
  }
}

// ---------------- launcher ----------------
extern "C" void kernel_launch(void* const* d_in, const int* in_sizes, int n_in,
                              void* d_out, int out_size, void* d_ws, size_t ws_size,
                              hipStream_t stream) {
  const float* x        = (const float*)d_in[0];
  const float* norm1_g  = (const float*)d_in[1];
  const float* norm1_b  = (const float*)d_in[2];
  const float* qkv_w    = (const float*)d_in[3];
  const float* qkv_b    = (const float*)d_in[4];
  const float* proj_w   = (const float*)d_in[5];
  const float* proj_b   = (const float*)d_in[6];
  const float* rel_tab  = (const float*)d_in[7];
  const float* norm2_g  = (const float*)d_in[8];
  const float* norm2_b  = (const float*)d_in[9];
  const float* fc1_w    = (const float*)d_in[10];
  const float* fc1_b    = (const float*)d_in[11];
  const float* fc2_w    = (const float*)d_in[12];
  const float* fc2_b    = (const float*)d_in[13];
  const int*   rel_idx  = (const int*)d_in[14];
  float* out = (float*)d_out;

  // workspace layout (bytes):
  //   [0,            38,535,168)  slotA: xw -> ao -> xn2   (bf16, M*192)
  //   [38,535,168,  154,140,672)  slotB: qkv -> hbuf(half) (bf16)
  //   [154,140,672, 231,211,008)  x1 fp32 (B,H,W,C) residual trunk
  char* ws = (char*)d_ws;
  bf16*  xw   = (bf16*)ws;
  bf16*  qkv  = (bf16*)(ws + 38535168);
  float* x1   = (float*)(ws + 154140672);
  bf16*  ao   = xw;   // reuse after qkv GEMM consumed xw
  bf16*  xn2  = xw;   // reuse after proj GEMM consumed ao
  bf16*  hbuf = qkv;  // reuse after attention consumed qkv

  // 1) LN1 + shift + partition
  k_ln1_part<<<MTOK / 4, 256, 0, stream>>>(x, norm1_g, norm1_b, xw);
  // 2) qkv GEMM (M x 192) @ (576 x 192)^T
  k_gemm<0><<<dim3(576 / 64, MTOK / 64), 256, 0, stream>>>(
      xw, qkv_w, qkv_b, qkv, nullptr, 192);
  // 3) windowed attention
  k_attn<<<NWIN * NHEADS, 256, 0, stream>>>(qkv, rel_tab, rel_idx, ao);
  // 4) proj GEMM + window-reverse + roll + residual -> x1 (fp32)
  k_gemm<1><<<dim3(192 / 64, MTOK / 64), 256, 0, stream>>>(
      ao, proj_w, proj_b, x1, x, 192);
  // 5) LN2
  k_ln2<<<MTOK / 4, 256, 0, stream>>>(x1, norm2_g, norm2_b, xn2);
  // 6/7) MLP in two token halves (hbuf reuses qkv slot)
  const int MH = MTOK / 2;  // 50176
  for (int h = 0; h < 2; ++h) {
    size_t mo = (size_t)h * MH;
    k_gemm<2><<<dim3(HIDDEN / 64, MH / 64), 256, 0, stream>>>(
        xn2 + mo * CC, fc1_w, fc1_b, hbuf, nullptr, 192);
    k_gemm<3><<<dim3(CC / 64, MH / 64), 256, 0, stream>>>(
        hbuf, fc2_w, fc2_b, out + mo * CC, x1 + mo * CC, 768);
  }
}

// Round 3
// 735.633 us; speedup vs baseline: 3.2455x; 3.2455x over previous
//
#include <hip/hip_runtime.h>
#include <hip/hip_bf16.h>

// ---------------- problem constants ----------------
#define CC 192
#define NHEADS 6
#define HDIM 32
#define NTOK 49          // tokens per window
#define NWIN 2048        // 32 * 8 * 8
#define MTOK 100352      // NWIN * NTOK == B*H*W
#define HIDDEN 768

typedef __hip_bfloat16 bf16;
typedef __attribute__((ext_vector_type(8))) short short8;
typedef __attribute__((ext_vector_type(4))) float f32x4;

// ---------------- weight fp32 -> bf16 conversion ----------------
// wbuf layout: qkv_w[110592] | proj_w[36864] | fc1_w[147456] | fc2_w[147456]
__global__ __launch_bounds__(256) void k_wconv(
    const float* __restrict__ qw, const float* __restrict__ pw,
    const float* __restrict__ f1, const float* __restrict__ f2,
    bf16* __restrict__ o) {
  int i = blockIdx.x * 256 + threadIdx.x;
  if (i < 110592) o[i] = __float2bfloat16(qw[i]);
  else if (i < 147456) o[i] = __float2bfloat16(pw[i - 110592]);
  else if (i < 294912) o[i] = __float2bfloat16(f1[i - 147456]);
  else if (i < 442368) o[i] = __float2bfloat16(f2[i - 294912]);
}

// ---------------- kernel: LN1 + roll(-3,-3) + window partition ----------
__global__ __launch_bounds__(256) void k_ln1_part(
    const float* __restrict__ x, const float* __restrict__ g,
    const float* __restrict__ bta, bf16* __restrict__ xw) {
  int wv = blockIdx.x * 4 + (threadIdx.x >> 6);
  int lane = threadIdx.x & 63;
  int w = wv / NTOK, n = wv - w * NTOK;
  int b = w >> 6, wrem = w & 63;
  int hi = wrem >> 3, wi = wrem & 7;
  int i = n / 7, j = n - i * 7;
  int hsrc = hi * 7 + i + 3; if (hsrc >= 56) hsrc -= 56;
  int wsrc = wi * 7 + j + 3; if (wsrc >= 56) wsrc -= 56;
  const float* row = x + (size_t)((b * 56 + hsrc) * 56 + wsrc) * CC;
  float v0 = row[lane], v1 = row[lane + 64], v2 = row[lane + 128];
  float s = v0 + v1 + v2;
  for (int m = 32; m; m >>= 1) s += __shfl_xor(s, m, 64);
  float mu = s * (1.0f / 192.0f);
  float d0 = v0 - mu, d1 = v1 - mu, d2 = v2 - mu;
  float q = d0 * d0 + d1 * d1 + d2 * d2;
  for (int m = 32; m; m >>= 1) q += __shfl_xor(q, m, 64);
  float inv = rsqrtf(q * (1.0f / 192.0f) + 1e-5f);
  bf16* orow = xw + (size_t)wv * CC;
  orow[lane]       = __float2bfloat16(d0 * inv * g[lane]       + bta[lane]);
  orow[lane + 64]  = __float2bfloat16(d1 * inv * g[lane + 64]  + bta[lane + 64]);
  orow[lane + 128] = __float2bfloat16(d2 * inv * g[lane + 128] + bta[lane + 128]);
}

// ---------------- kernel: LN2 (fp32 in, bf16 out, row-major) ----------
__global__ __launch_bounds__(256) void k_ln2(
    const float* __restrict__ x1, const float* __restrict__ g,
    const float* __restrict__ bta, bf16* __restrict__ xn2) {
  int wv = blockIdx.x * 4 + (threadIdx.x >> 6);
  int lane = threadIdx.x & 63;
  const float* row = x1 + (size_t)wv * CC;
  float v0 = row[lane], v1 = row[lane + 64], v2 = row[lane + 128];
  float s = v0 + v1 + v2;
  for (int m = 32; m; m >>= 1) s += __shfl_xor(s, m, 64);
  float mu = s * (1.0f / 192.0f);
  float d0 = v0 - mu, d1 = v1 - mu, d2 = v2 - mu;
  float q = d0 * d0 + d1 * d1 + d2 * d2;
  for (int m = 32; m; m >>= 1) q += __shfl_xor(q, m, 64);
  float inv = rsqrtf(q * (1.0f / 192.0f) + 1e-5f);
  bf16* orow = xn2 + (size_t)wv * CC;
  orow[lane]       = __float2bfloat16(d0 * inv * g[lane]       + bta[lane]);
  orow[lane + 64]  = __float2bfloat16(d1 * inv * g[lane + 64]  + bta[lane + 64]);
  orow[lane + 128] = __float2bfloat16(d2 * inv * g[lane + 128] + bta[lane + 128]);
}

// ---------------- MFMA GEMM: out[m,n] = A[m,:] . W[n,:] + bias[n] --------
// A bf16 [M,K] row-major, W bf16 [N,K] row-major.
// Block: 256 thr = 4 waves; tile M=256, N=64, BK=32; wave = 64x64 subtile.
// MODE 0: row-major bf16 (qkv)        MODE 1: proj + reverse/roll + residual
// MODE 2: fc1 + GELU (bf16)           MODE 3: fc2 + residual (fp32 natural)
template <int MODE>
__global__ __launch_bounds__(256) void k_mgemm(
    const bf16* __restrict__ A, const bf16* __restrict__ W,
    const float* __restrict__ bias, void* __restrict__ out0,
    const void* __restrict__ aux, int K, int N) {
  __shared__ bf16 As[256 * 32];  // 16 KB, row-major [m][k]
  __shared__ bf16 Bs[64 * 32];   //  4 KB, row-major [n][k]
  const int tid = threadIdx.x;
  const int wave = tid >> 6, lane = tid & 63;
  const int m0 = blockIdx.y * 256, n0 = blockIdx.x * 64;
  f32x4 acc[4][4] = {};

  const int kq = (lane >> 4) * 8;  // k offset within 32 (0/8/16/24)
  const int rA = lane & 15;

  for (int kt = 0; kt < K; kt += 32) {
    // stage A-tile: 1024 slots of 16B; slot s -> row s/4, kpart s%4
#pragma unroll
    for (int it = 0; it < 4; ++it) {
      int s = it * 256 + tid;
      const bf16* g = A + (size_t)(m0 + (s >> 2)) * K + kt + (s & 3) * 8;
      __builtin_amdgcn_global_load_lds(
          (const __attribute__((address_space(1))) void*)g,
          (__attribute__((address_space(3))) void*)(&As[s * 8]), 16, 0, 0);
    }
    // stage B-tile: 256 slots
    {
      int s = tid;
      const bf16* g = W + (size_t)(n0 + (s >> 2)) * K + kt + (s & 3) * 8;
      __builtin_amdgcn_global_load_lds(
          (const __attribute__((address_space(1))) void*)g,
          (__attribute__((address_space(3))) void*)(&Bs[s * 8]), 16, 0, 0);
    }
    __syncthreads();
    short8 a[4], b[4];
#pragma unroll
    for (int mt = 0; mt < 4; ++mt)
      a[mt] = *(const short8*)&As[(wave * 64 + mt * 16 + rA) * 32 + kq];
#pragma unroll
    for (int nt = 0; nt < 4; ++nt)
      b[nt] = *(const short8*)&Bs[(nt * 16 + rA) * 32 + kq];
#pragma unroll
    for (int mt = 0; mt < 4; ++mt)
#pragma unroll
      for (int nt = 0; nt < 4; ++nt)
        acc[mt][nt] = __builtin_amdgcn_mfma_f32_16x16x32_bf16(
            a[mt], b[nt], acc[mt][nt], 0, 0, 0);
    __syncthreads();
  }

  // epilogue: lane holds D[row = (lane>>4)*4 + r][col = lane&15] per tile
  const int cq = lane >> 4;
  const int cn = lane & 15;
  float bi[4];
#pragma unroll
  for (int nt = 0; nt < 4; ++nt) bi[nt] = bias[n0 + nt * 16 + cn];

#pragma unroll
  for (int mt = 0; mt < 4; ++mt) {
#pragma unroll
    for (int r = 0; r < 4; ++r) {
      int m = m0 + wave * 64 + mt * 16 + cq * 4 + r;
      size_t rowoff;
      if (MODE == 1) {  // window-reverse + roll(+3,+3) pixel
        int w = m / 49, rr = m - w * 49;
        int b = w >> 6, wrem = w & 63;
        int hi = wrem >> 3, wi = wrem & 7;
        int ii = rr / 7, jj = rr - ii * 7;
        int hd = hi * 7 + ii + 3; if (hd >= 56) hd -= 56;
        int wd = wi * 7 + jj + 3; if (wd >= 56) wd -= 56;
        rowoff = (size_t)((b * 56 + hd) * 56 + wd) * CC;
      }
#pragma unroll
      for (int nt = 0; nt < 4; ++nt) {
        int n = n0 + nt * 16 + cn;
        float v = acc[mt][nt][r] + bi[nt];
        if (MODE == 0) {
          ((bf16*)out0)[(size_t)m * N + n] = __float2bfloat16(v);
        } else if (MODE == 2) {
          float ge = 0.5f * v * (1.0f + erff(v * 0.70710678118654752f));
          ((bf16*)out0)[(size_t)m * N + n] = __float2bfloat16(ge);
        } else if (MODE == 1) {
          float res = ((const float*)aux)[rowoff + n];
          ((float*)out0)[rowoff + n] = v + res;
        } else {
          float res = ((const float*)aux)[(size_t)m * CC + n];
          ((float*)out0)[(size_t)m * CC + n] = v + res;
        }
      }
    }
  }
}

// ---------------- attention: one block per (window, head) ----------------
// qkv layout: [M, 576] row-major; q = cols [0,192), k [192,384), v [384,576)
__global__ __launch_bounds__(256) void k_attn(
    const bf16* __restrict__ qkv, const float* __restrict__ table,
    const int* __restrict__ ridx, bf16* __restrict__ ao) {
  __shared__ float qs[49 * 33];
  __shared__ float ks[49 * 33];
  __shared__ float vs[49 * 33];
  __shared__ float S[49 * 50];
  int w = blockIdx.x / NHEADS, hh = blockIdx.x - w * NHEADS;
  for (int e = threadIdx.x; e < 1568; e += 256) {
    int r = e >> 5, d = e & 31;
    size_t base = (size_t)(w * NTOK + r) * 576 + hh * HDIM + d;
    qs[r * 33 + d] = __bfloat162float(qkv[base]);
    ks[r * 33 + d] = __bfloat162float(qkv[base + 192]);
    vs[r * 33 + d] = __bfloat162float(qkv[base + 384]);
  }
  __syncthreads();
  for (int e = threadIdx.x; e < 2401; e += 256) {
    int r = e / 49, c = e - r * 49;
    float acc = 0.0f;
#pragma unroll
    for (int kk = 0; kk < 32; ++kk) acc += qs[r * 33 + kk] * ks[c * 33 + kk];
    float bia = table[ridx[e] * NHEADS + hh];
    S[r * 50 + c] = acc * 0.17677669529663687f + bia;
  }
  __syncthreads();
  if (threadIdx.x < 49) {
    int r = threadIdx.x;
    float mx = -1e30f;
    for (int c = 0; c < 49; ++c) mx = fmaxf(mx, S[r * 50 + c]);
    float sum = 0.0f;
    for (int c = 0; c < 49; ++c) {
      float e2 = __expf(S[r * 50 + c] - mx);
      S[r * 50 + c] = e2;
      sum += e2;
    }
    float inv = 1.0f / sum;
    for (int c = 0; c < 49; ++c) S[r * 50 + c] *= inv;
  }
  __syncthreads();
  for (int e = threadIdx.x; e < 1568; e += 256) {
    int r = e >> 5, d = e & 31;
    float acc = 0.0f;
#pragma unroll
    for (int c = 0; c < 49; ++c) acc += S[r * 50 + c] * vs[c * 33 + d];
    ao[((size_t)w * NTOK + r) * CC + hh * HDIM + d] = __float2bfloat16(acc);
  }
}

// ---------------- launcher ----------------
extern "C" void kernel_launch(void* const* d_in, const int* in_sizes, int n_in,
                              void* d_out, int out_size, void* d_ws, size_t ws_size,
                              hipStream_t stream) {
  const float* x        = (const float*)d_in[0];
  const float* norm1_g  = (const float*)d_in[1];
  const float* norm1_b  = (const float*)d_in[2];
  const float* qkv_w    = (const float*)d_in[3];
  const float* qkv_b    = (const float*)d_in[4];
  const float* proj_w   = (const float*)d_in[5];
  const float* proj_b   = (const float*)d_in[6];
  const float* rel_tab  = (const float*)d_in[7];
  const float* norm2_g  = (const float*)d_in[8];
  const float* norm2_b  = (const float*)d_in[9];
  const float* fc1_w    = (const float*)d_in[10];
  const float* fc1_b    = (const float*)d_in[11];
  const float* fc2_w    = (const float*)d_in[12];
  const float* fc2_b    = (const float*)d_in[13];
  const int*   rel_idx  = (const int*)d_in[14];
  float* out = (float*)d_out;

  // workspace layout (bytes):
  //   [0,           38,535,168)  slotA: xw -> ao -> xn2     (bf16 M*192)
  //   [38,535,168, 154,140,672)  slotB: qkv[M,576] -> hbuf  (bf16)
  //   [154,140,672, ...+884,736) wbuf: bf16 weights
  // fp32 residual trunk x1 lives in d_out (overwritten in-place by fc2).
  char* ws = (char*)d_ws;
  bf16*  xw   = (bf16*)ws;
  bf16*  qkvb = (bf16*)(ws + 38535168);
  bf16*  wbuf = (bf16*)(ws + 154140672);
  bf16*  ao   = xw;
  bf16*  xn2  = xw;
  bf16*  hbuf = qkvb;
  float* x1   = out;
  bf16* wq = wbuf;
  bf16* wp = wbuf + 110592;
  bf16* w1 = wbuf + 147456;
  bf16* w2 = wbuf + 294912;

  k_wconv<<<1728, 256, 0, stream>>>(qkv_w, proj_w, fc1_w, fc2_w, wbuf);
  k_ln1_part<<<MTOK / 4, 256, 0, stream>>>(x, norm1_g, norm1_b, xw);
  // qkv: [M,192] @ [576,192]^T -> [M,576]
  k_mgemm<0><<<dim3(576 / 64, MTOK / 256), 256, 0, stream>>>(
      xw, wq, qkv_b, qkvb, nullptr, 192, 576);
  k_attn<<<NWIN * NHEADS, 256, 0, stream>>>(qkvb, rel_tab, rel_idx, ao);
  // proj + reverse/roll + residual -> x1 (d_out, fp32 natural order)
  k_mgemm<1><<<dim3(192 / 64, MTOK / 256), 256, 0, stream>>>(
      ao, wp, proj_b, x1, x, 192, 192);
  k_ln2<<<MTOK / 4, 256, 0, stream>>>(x1, norm2_g, norm2_b, xn2);
  // MLP in two token halves (hbuf reuses qkv slot)
  const int MH = MTOK / 2;  // 50176
  for (int h = 0; h < 2; ++h) {
    size_t mo = (size_t)h * MH;
    k_mgemm<2><<<dim3(HIDDEN / 64, MH / 256), 256, 0, stream>>>(
        xn2 + mo * CC, w1, fc1_b, hbuf, nullptr, 192, 768);
    k_mgemm<3><<<dim3(CC / 64, MH / 256), 256, 0, stream>>>(
        hbuf, w2, fc2_b, out + mo * CC, x1 + mo * CC, 768, 192);
  }
}

// Round 4
// 618.757 us; speedup vs baseline: 3.8585x; 1.1889x over previous
//
#include <hip/hip_runtime.h>
#include <hip/hip_bf16.h>

// ---------------- problem constants ----------------
#define CC 192
#define NHEADS 6
#define HDIM 32
#define NTOK 49
#define NWIN 2048
#define MTOK 100352      // NWIN * NTOK
#define HIDDEN 768

typedef __hip_bfloat16 bf16;
typedef __attribute__((ext_vector_type(8))) short short8;
typedef __attribute__((ext_vector_type(4))) float f32x4;

// ---------------- weight fp32 -> bf16 conversion ----------------
__global__ __launch_bounds__(256) void k_wconv(
    const float* __restrict__ qw, const float* __restrict__ pw,
    const float* __restrict__ f1, const float* __restrict__ f2,
    bf16* __restrict__ o) {
  int i = blockIdx.x * 256 + threadIdx.x;
  if (i < 110592) o[i] = __float2bfloat16(qw[i]);
  else if (i < 147456) o[i] = __float2bfloat16(pw[i - 110592]);
  else if (i < 294912) o[i] = __float2bfloat16(f1[i - 147456]);
  else if (i < 442368) o[i] = __float2bfloat16(f2[i - 294912]);
}

// ---------------- bias6[h][49][49] = table[ridx[r*49+c]*6+h] -------------
__global__ __launch_bounds__(256) void k_bias(
    const float* __restrict__ table, const int* __restrict__ ridx,
    float* __restrict__ bias6) {
  int i = blockIdx.x * 256 + threadIdx.x;
  if (i >= 6 * 2401) return;
  int h = i / 2401, e = i - h * 2401;
  bias6[i] = table[ridx[e] * NHEADS + h];
}

// ---------------- LN1 + roll(-3,-3) + window partition ----------
__global__ __launch_bounds__(256) void k_ln1_part(
    const float* __restrict__ x, const float* __restrict__ g,
    const float* __restrict__ bta, bf16* __restrict__ xw) {
  int wv = blockIdx.x * 4 + (threadIdx.x >> 6);
  int lane = threadIdx.x & 63;
  int w = wv / NTOK, n = wv - w * NTOK;
  int b = w >> 6, wrem = w & 63;
  int hi = wrem >> 3, wi = wrem & 7;
  int i = n / 7, j = n - i * 7;
  int hsrc = hi * 7 + i + 3; if (hsrc >= 56) hsrc -= 56;
  int wsrc = wi * 7 + j + 3; if (wsrc >= 56) wsrc -= 56;
  const float* row = x + (size_t)((b * 56 + hsrc) * 56 + wsrc) * CC;
  float v0 = row[lane], v1 = row[lane + 64], v2 = row[lane + 128];
  float s = v0 + v1 + v2;
  for (int m = 32; m; m >>= 1) s += __shfl_xor(s, m, 64);
  float mu = s * (1.0f / 192.0f);
  float d0 = v0 - mu, d1 = v1 - mu, d2 = v2 - mu;
  float q = d0 * d0 + d1 * d1 + d2 * d2;
  for (int m = 32; m; m >>= 1) q += __shfl_xor(q, m, 64);
  float inv = rsqrtf(q * (1.0f / 192.0f) + 1e-5f);
  bf16* orow = xw + (size_t)wv * CC;
  orow[lane]       = __float2bfloat16(d0 * inv * g[lane]       + bta[lane]);
  orow[lane + 64]  = __float2bfloat16(d1 * inv * g[lane + 64]  + bta[lane + 64]);
  orow[lane + 128] = __float2bfloat16(d2 * inv * g[lane + 128] + bta[lane + 128]);
}

// ---------------- LN2 (fp32 in, bf16 out, row-major) ----------
__global__ __launch_bounds__(256) void k_ln2(
    const float* __restrict__ x1, const float* __restrict__ g,
    const float* __restrict__ bta, bf16* __restrict__ xn2) {
  int wv = blockIdx.x * 4 + (threadIdx.x >> 6);
  int lane = threadIdx.x & 63;
  const float* row = x1 + (size_t)wv * CC;
  float v0 = row[lane], v1 = row[lane + 64], v2 = row[lane + 128];
  float s = v0 + v1 + v2;
  for (int m = 32; m; m >>= 1) s += __shfl_xor(s, m, 64);
  float mu = s * (1.0f / 192.0f);
  float d0 = v0 - mu, d1 = v1 - mu, d2 = v2 - mu;
  float q = d0 * d0 + d1 * d1 + d2 * d2;
  for (int m = 32; m; m >>= 1) q += __shfl_xor(q, m, 64);
  float inv = rsqrtf(q * (1.0f / 192.0f) + 1e-5f);
  bf16* orow = xn2 + (size_t)wv * CC;
  orow[lane]       = __float2bfloat16(d0 * inv * g[lane]       + bta[lane]);
  orow[lane + 64]  = __float2bfloat16(d1 * inv * g[lane + 64]  + bta[lane + 64]);
  orow[lane + 128] = __float2bfloat16(d2 * inv * g[lane + 128] + bta[lane + 128]);
}

// ---------------- MFMA GEMM: out[m,n] = A[m,:] . W[n,:] + bias[n] --------
// MODE 0: qkv -> qk[M,384] + vT[win][head][32][64]  (out1 = vT)
// MODE 1: proj + reverse/roll + residual (fp32)
// MODE 2: fc1 + GELU (bf16)   MODE 3: fc2 + residual (fp32)
template <int MODE>
__global__ __launch_bounds__(256) void k_mgemm(
    const bf16* __restrict__ A, const bf16* __restrict__ W,
    const float* __restrict__ bias, void* __restrict__ out0,
    void* __restrict__ out1, const void* __restrict__ aux, int K, int N) {
  __shared__ bf16 As[256 * 32];
  __shared__ bf16 Bs[64 * 32];
  const int tid = threadIdx.x;
  const int wave = tid >> 6, lane = tid & 63;
  const int m0 = blockIdx.y * 256, n0 = blockIdx.x * 64;
  f32x4 acc[4][4] = {};
  const int kq = (lane >> 4) * 8;
  const int rA = lane & 15;

  for (int kt = 0; kt < K; kt += 32) {
#pragma unroll
    for (int it = 0; it < 4; ++it) {
      int s = it * 256 + tid;
      const bf16* g = A + (size_t)(m0 + (s >> 2)) * K + kt + (s & 3) * 8;
      __builtin_amdgcn_global_load_lds(
          (const __attribute__((address_space(1))) void*)g,
          (__attribute__((address_space(3))) void*)(&As[s * 8]), 16, 0, 0);
    }
    {
      int s = tid;
      const bf16* g = W + (size_t)(n0 + (s >> 2)) * K + kt + (s & 3) * 8;
      __builtin_amdgcn_global_load_lds(
          (const __attribute__((address_space(1))) void*)g,
          (__attribute__((address_space(3))) void*)(&Bs[s * 8]), 16, 0, 0);
    }
    __syncthreads();
    short8 a[4], b[4];
#pragma unroll
    for (int mt = 0; mt < 4; ++mt)
      a[mt] = *(const short8*)&As[(wave * 64 + mt * 16 + rA) * 32 + kq];
#pragma unroll
    for (int nt = 0; nt < 4; ++nt)
      b[nt] = *(const short8*)&Bs[(nt * 16 + rA) * 32 + kq];
#pragma unroll
    for (int mt = 0; mt < 4; ++mt)
#pragma unroll
      for (int nt = 0; nt < 4; ++nt)
        acc[mt][nt] = __builtin_amdgcn_mfma_f32_16x16x32_bf16(
            a[mt], b[nt], acc[mt][nt], 0, 0, 0);
    __syncthreads();
  }

  const int cq = lane >> 4;
  const int cn = lane & 15;
  float bi[4];
#pragma unroll
  for (int nt = 0; nt < 4; ++nt) bi[nt] = bias[n0 + nt * 16 + cn];

#pragma unroll
  for (int mt = 0; mt < 4; ++mt) {
#pragma unroll
    for (int r = 0; r < 4; ++r) {
      int m = m0 + wave * 64 + mt * 16 + cq * 4 + r;
      size_t rowoff = 0;
      int wv = 0, tok = 0;
      if (MODE == 0) { wv = m / 49; tok = m - wv * 49; }
      if (MODE == 1) {
        int w = m / 49, rr = m - w * 49;
        int b = w >> 6, wrem = w & 63;
        int hi = wrem >> 3, wi = wrem & 7;
        int ii = rr / 7, jj = rr - ii * 7;
        int hd = hi * 7 + ii + 3; if (hd >= 56) hd -= 56;
        int wd = wi * 7 + jj + 3; if (wd >= 56) wd -= 56;
        rowoff = (size_t)((b * 56 + hd) * 56 + wd) * CC;
      }
#pragma unroll
      for (int nt = 0; nt < 4; ++nt) {
        int n = n0 + nt * 16 + cn;
        float v = acc[mt][nt][r] + bi[nt];
        if (MODE == 0) {
          if (n < 384) {
            ((bf16*)out0)[(size_t)m * 384 + n] = __float2bfloat16(v);
          } else {
            int hh = (n - 384) >> 5, d = (n - 384) & 31;
            ((bf16*)out1)[((size_t)(wv * NHEADS + hh) * 32 + d) * 64 + tok] =
                __float2bfloat16(v);
          }
        } else if (MODE == 2) {
          float ge = 0.5f * v * (1.0f + erff(v * 0.70710678118654752f));
          ((bf16*)out0)[(size_t)m * N + n] = __float2bfloat16(ge);
        } else if (MODE == 1) {
          float res = ((const float*)aux)[rowoff + n];
          ((float*)out0)[rowoff + n] = v + res;
        } else {
          float res = ((const float*)aux)[(size_t)m * CC + n];
          ((float*)out0)[(size_t)m * CC + n] = v + res;
        }
      }
    }
  }
}

// ---------------- MFMA attention: 1 wave per (window,head) ---------------
// qk: [M,384] (q cols 0..191, k cols 192..383); vT: [win][head][32][64]
__global__ __launch_bounds__(256) void k_attn_mfma(
    const bf16* __restrict__ qk, const bf16* __restrict__ vT,
    const float* __restrict__ bias6, bf16* __restrict__ ao) {
  __shared__ bf16 P[4][64 * 72];  // per-wave P buffer, stride 72 (144B rows)
  const int wave = threadIdx.x >> 6, lane = threadIdx.x & 63;
  const int wh = blockIdx.x * 4 + wave;
  const int w = wh / NHEADS, h = wh - w * NHEADS;
  const int rA = lane & 15, kq = (lane >> 4) * 8;
  const int grp = lane >> 4;

  // ---- QK^T: fragments straight from global ----
  short8 aq[4], bk[4];
  const bf16* qbase = qk + (size_t)(w * 49) * 384 + h * HDIM + kq;
#pragma unroll
  for (int t = 0; t < 4; ++t) {
    aq[t] = *(const short8*)(qbase + (size_t)(t * 16 + rA) * 384);
    bk[t] = *(const short8*)(qbase + 192 + (size_t)(t * 16 + rA) * 384);
  }
  f32x4 S[4][4] = {};
#pragma unroll
  for (int mt = 0; mt < 4; ++mt)
#pragma unroll
    for (int nt = 0; nt < 4; ++nt)
      S[mt][nt] = __builtin_amdgcn_mfma_f32_16x16x32_bf16(
          aq[mt], bk[nt], S[mt][nt], 0, 0, 0);

  // ---- softmax over rows (row lives in one 16-lane group + 4 nt regs) ----
  const float scale = 0.17677669529663687f;
  const float* bh = bias6 + h * 2401;
  float rs[4][4];
  bf16* Pw = P[wave];
#pragma unroll
  for (int mt = 0; mt < 4; ++mt) {
#pragma unroll
    for (int r = 0; r < 4; ++r) {
      int row = mt * 16 + grp * 4 + r;
      float val[4];
#pragma unroll
      for (int nt = 0; nt < 4; ++nt) {
        int c = nt * 16 + rA;
        float bv = (row < 49 && c < 49) ? bh[row * 49 + c] : 0.0f;
        val[nt] = (c < 49) ? (S[mt][nt][r] * scale + bv) : -1e30f;
      }
      float mx = fmaxf(fmaxf(val[0], val[1]), fmaxf(val[2], val[3]));
      for (int m2 = 1; m2 < 16; m2 <<= 1) mx = fmaxf(mx, __shfl_xor(mx, m2, 64));
      float sum = 0.0f;
#pragma unroll
      for (int nt = 0; nt < 4; ++nt) {
        float e = __expf(val[nt] - mx);
        val[nt] = e;
        sum += e;
      }
      for (int m2 = 1; m2 < 16; m2 <<= 1) sum += __shfl_xor(sum, m2, 64);
      rs[mt][r] = 1.0f / sum;
#pragma unroll
      for (int nt = 0; nt < 4; ++nt)
        Pw[row * 72 + nt * 16 + rA] = __float2bfloat16(val[nt]);
    }
  }
  __syncthreads();

  // ---- PV: A-frags from P-LDS, B-frags (V^T) from global ----
  const bf16* vbase = vT + (size_t)wh * (32 * 64);
  short8 bv[2][2];
#pragma unroll
  for (int ks = 0; ks < 2; ++ks)
#pragma unroll
    for (int nt = 0; nt < 2; ++nt)
      bv[ks][nt] = *(const short8*)(vbase + (size_t)(nt * 16 + rA) * 64 +
                                    ks * 32 + kq);
  f32x4 O[4][2] = {};
#pragma unroll
  for (int mt = 0; mt < 4; ++mt) {
    short8 ap0 = *(const short8*)&Pw[(mt * 16 + rA) * 72 + kq];
    short8 ap1 = *(const short8*)&Pw[(mt * 16 + rA) * 72 + 32 + kq];
#pragma unroll
    for (int nt = 0; nt < 2; ++nt) {
      O[mt][nt] = __builtin_amdgcn_mfma_f32_16x16x32_bf16(ap0, bv[0][nt],
                                                          O[mt][nt], 0, 0, 0);
      O[mt][nt] = __builtin_amdgcn_mfma_f32_16x16x32_bf16(ap1, bv[1][nt],
                                                          O[mt][nt], 0, 0, 0);
    }
  }
  // ---- write O (rows m<49), normalized by row sums ----
#pragma unroll
  for (int mt = 0; mt < 4; ++mt) {
#pragma unroll
    for (int r = 0; r < 4; ++r) {
      int m = mt * 16 + grp * 4 + r;
      if (m < 49) {
        bf16* orow = ao + (size_t)(w * 49 + m) * CC + h * HDIM;
#pragma unroll
        for (int nt = 0; nt < 2; ++nt)
          orow[nt * 16 + rA] = __float2bfloat16(O[mt][nt][r] * rs[mt][r]);
      }
    }
  }
}

// ---------------- launcher ----------------
extern "C" void kernel_launch(void* const* d_in, const int* in_sizes, int n_in,
                              void* d_out, int out_size, void* d_ws, size_t ws_size,
                              hipStream_t stream) {
  const float* x        = (const float*)d_in[0];
  const float* norm1_g  = (const float*)d_in[1];
  const float* norm1_b  = (const float*)d_in[2];
  const float* qkv_w    = (const float*)d_in[3];
  const float* qkv_b    = (const float*)d_in[4];
  const float* proj_w   = (const float*)d_in[5];
  const float* proj_b   = (const float*)d_in[6];
  const float* rel_tab  = (const float*)d_in[7];
  const float* norm2_g  = (const float*)d_in[8];
  const float* norm2_b  = (const float*)d_in[9];
  const float* fc1_w    = (const float*)d_in[10];
  const float* fc1_b    = (const float*)d_in[11];
  const float* fc2_w    = (const float*)d_in[12];
  const float* fc2_b    = (const float*)d_in[13];
  const int*   rel_idx  = (const int*)d_in[14];
  float* out = (float*)d_out;

  // workspace layout (bytes):
  //   [0,           38,535,168)   slotA: xw -> ao -> xn2       (bf16 M*192)
  //   [38,535,168, 115,605,504)   qk [M,384] bf16 (later hbuf, 77,070,336 B)
  //   [115,605,504,165,937,152)   vT [2048*6*32*64] bf16 (50,331,648 B)
  //   [165,937,152,166,821,888)   wbuf bf16 weights (884,736 B)
  //   [166,821,888,166,879,512)   bias6 fp32 (57,624 B)
  char* ws = (char*)d_ws;
  bf16*  xw    = (bf16*)ws;
  bf16*  qkb   = (bf16*)(ws + 38535168);
  bf16*  vT    = (bf16*)(ws + 115605504);
  bf16*  wbuf  = (bf16*)(ws + 165937152);
  float* bias6 = (float*)(ws + 166821888);
  bf16*  ao    = xw;
  bf16*  xn2   = xw;
  bf16*  hbuf  = qkb;   // 77,070,336 B, exactly MH*768*2
  float* x1    = out;   // fp32 residual trunk lives in d_out
  bf16* wq = wbuf;
  bf16* wp = wbuf + 110592;
  bf16* w1 = wbuf + 147456;
  bf16* w2 = wbuf + 294912;

  k_wconv<<<1728, 256, 0, stream>>>(qkv_w, proj_w, fc1_w, fc2_w, wbuf);
  k_bias<<<57, 256, 0, stream>>>(rel_tab, rel_idx, bias6);
  hipMemsetAsync(vT, 0, 50331648, stream);  // zero tok-padding of vT
  k_ln1_part<<<MTOK / 4, 256, 0, stream>>>(x, norm1_g, norm1_b, xw);
  // qkv: [M,192] @ [576,192]^T -> qk[M,384] + vT
  k_mgemm<0><<<dim3(576 / 64, MTOK / 256), 256, 0, stream>>>(
      xw, wq, qkv_b, qkb, vT, nullptr, 192, 576);
  k_attn_mfma<<<NWIN * NHEADS / 4, 256, 0, stream>>>(qkb, vT, bias6, ao);
  // proj + reverse/roll + residual -> x1 (d_out, fp32 natural order)
  k_mgemm<1><<<dim3(192 / 64, MTOK / 256), 256, 0, stream>>>(
      ao, wp, proj_b, x1, nullptr, x, 192, 192);
  k_ln2<<<MTOK / 4, 256, 0, stream>>>(x1, norm2_g, norm2_b, xn2);
  const int MH = MTOK / 2;  // 50176
  for (int h = 0; h < 2; ++h) {
    size_t mo = (size_t)h * MH;
    k_mgemm<2><<<dim3(HIDDEN / 64, MH / 256), 256, 0, stream>>>(
        xn2 + mo * CC, w1, fc1_b, hbuf, nullptr, nullptr, 192, 768);
    k_mgemm<3><<<dim3(CC / 64, MH / 256), 256, 0, stream>>>(
        hbuf, w2, fc2_b, out + mo * CC, nullptr, x1 + mo * CC, 768, 192);
  }
}

// Round 5
// 598.516 us; speedup vs baseline: 3.9890x; 1.0338x over previous
//
#include <hip/hip_runtime.h>
#include <hip/hip_bf16.h>

// ---------------- problem constants ----------------
#define CC 192
#define NHEADS 6
#define HDIM 32
#define NTOK 49
#define NWIN 2048
#define MTOK 100352      // NWIN * NTOK
#define HIDDEN 768

typedef __hip_bfloat16 bf16;
typedef __attribute__((ext_vector_type(8))) short short8;
typedef __attribute__((ext_vector_type(4))) float f32x4;

// ---------------- weight fp32 -> bf16 conversion ----------------
__global__ __launch_bounds__(256) void k_wconv(
    const float* __restrict__ qw, const float* __restrict__ pw,
    const float* __restrict__ f1, const float* __restrict__ f2,
    bf16* __restrict__ o) {
  int i = blockIdx.x * 256 + threadIdx.x;
  if (i < 110592) o[i] = __float2bfloat16(qw[i]);
  else if (i < 147456) o[i] = __float2bfloat16(pw[i - 110592]);
  else if (i < 294912) o[i] = __float2bfloat16(f1[i - 147456]);
  else if (i < 442368) o[i] = __float2bfloat16(f2[i - 294912]);
}

// ---------------- bias6[h][49][49] = table[ridx[r*49+c]*6+h] -------------
__global__ __launch_bounds__(256) void k_bias(
    const float* __restrict__ table, const int* __restrict__ ridx,
    float* __restrict__ bias6) {
  int i = blockIdx.x * 256 + threadIdx.x;
  if (i >= 6 * 2401) return;
  int h = i / 2401, e = i - h * 2401;
  bias6[i] = table[ridx[e] * NHEADS + h];
}

// ---------------- LN1 + roll(-3,-3) + window partition ----------
__global__ __launch_bounds__(256) void k_ln1_part(
    const float* __restrict__ x, const float* __restrict__ g,
    const float* __restrict__ bta, bf16* __restrict__ xw) {
  int wv = blockIdx.x * 4 + (threadIdx.x >> 6);
  int lane = threadIdx.x & 63;
  int w = wv / NTOK, n = wv - w * NTOK;
  int b = w >> 6, wrem = w & 63;
  int hi = wrem >> 3, wi = wrem & 7;
  int i = n / 7, j = n - i * 7;
  int hsrc = hi * 7 + i + 3; if (hsrc >= 56) hsrc -= 56;
  int wsrc = wi * 7 + j + 3; if (wsrc >= 56) wsrc -= 56;
  const float* row = x + (size_t)((b * 56 + hsrc) * 56 + wsrc) * CC;
  float v0 = row[lane], v1 = row[lane + 64], v2 = row[lane + 128];
  float s = v0 + v1 + v2;
  for (int m = 32; m; m >>= 1) s += __shfl_xor(s, m, 64);
  float mu = s * (1.0f / 192.0f);
  float d0 = v0 - mu, d1 = v1 - mu, d2 = v2 - mu;
  float q = d0 * d0 + d1 * d1 + d2 * d2;
  for (int m = 32; m; m >>= 1) q += __shfl_xor(q, m, 64);
  float inv = rsqrtf(q * (1.0f / 192.0f) + 1e-5f);
  bf16* orow = xw + (size_t)wv * CC;
  orow[lane]       = __float2bfloat16(d0 * inv * g[lane]       + bta[lane]);
  orow[lane + 64]  = __float2bfloat16(d1 * inv * g[lane + 64]  + bta[lane + 64]);
  orow[lane + 128] = __float2bfloat16(d2 * inv * g[lane + 128] + bta[lane + 128]);
}

// ---------------- LN2 (fp32 in, bf16 out, row-major) ----------
__global__ __launch_bounds__(256) void k_ln2(
    const float* __restrict__ x1, const float* __restrict__ g,
    const float* __restrict__ bta, bf16* __restrict__ xn2) {
  int wv = blockIdx.x * 4 + (threadIdx.x >> 6);
  int lane = threadIdx.x & 63;
  const float* row = x1 + (size_t)wv * CC;
  float v0 = row[lane], v1 = row[lane + 64], v2 = row[lane + 128];
  float s = v0 + v1 + v2;
  for (int m = 32; m; m >>= 1) s += __shfl_xor(s, m, 64);
  float mu = s * (1.0f / 192.0f);
  float d0 = v0 - mu, d1 = v1 - mu, d2 = v2 - mu;
  float q = d0 * d0 + d1 * d1 + d2 * d2;
  for (int m = 32; m; m >>= 1) q += __shfl_xor(q, m, 64);
  float inv = rsqrtf(q * (1.0f / 192.0f) + 1e-5f);
  bf16* orow = xn2 + (size_t)wv * CC;
  orow[lane]       = __float2bfloat16(d0 * inv * g[lane]       + bta[lane]);
  orow[lane + 64]  = __float2bfloat16(d1 * inv * g[lane + 64]  + bta[lane + 64]);
  orow[lane + 128] = __float2bfloat16(d2 * inv * g[lane + 128] + bta[lane + 128]);
}

// ---------------- MFMA GEMM: out[m,n] = A[m,:] . W[n,:] + bias[n] --------
// MODE 0: row-major bf16 out (qkv [M,576])
// MODE 1: proj + reverse/roll + residual (fp32)
// MODE 2: fc1 + GELU (bf16)   MODE 3: fc2 + residual (fp32)
template <int MODE>
__global__ __launch_bounds__(256) void k_mgemm(
    const bf16* __restrict__ A, const bf16* __restrict__ W,
    const float* __restrict__ bias, void* __restrict__ out0,
    const void* __restrict__ aux, int K, int N) {
  __shared__ bf16 As[256 * 32];
  __shared__ bf16 Bs[64 * 32];
  const int tid = threadIdx.x;
  const int wave = tid >> 6, lane = tid & 63;
  const int m0 = blockIdx.y * 256, n0 = blockIdx.x * 64;
  f32x4 acc[4][4] = {};
  const int kq = (lane >> 4) * 8;
  const int rA = lane & 15;

  for (int kt = 0; kt < K; kt += 32) {
#pragma unroll
    for (int it = 0; it < 4; ++it) {
      int s = it * 256 + tid;
      const bf16* g = A + (size_t)(m0 + (s >> 2)) * K + kt + (s & 3) * 8;
      __builtin_amdgcn_global_load_lds(
          (const __attribute__((address_space(1))) void*)g,
          (__attribute__((address_space(3))) void*)(&As[s * 8]), 16, 0, 0);
    }
    {
      int s = tid;
      const bf16* g = W + (size_t)(n0 + (s >> 2)) * K + kt + (s & 3) * 8;
      __builtin_amdgcn_global_load_lds(
          (const __attribute__((address_space(1))) void*)g,
          (__attribute__((address_space(3))) void*)(&Bs[s * 8]), 16, 0, 0);
    }
    __syncthreads();
    short8 a[4], b[4];
#pragma unroll
    for (int mt = 0; mt < 4; ++mt)
      a[mt] = *(const short8*)&As[(wave * 64 + mt * 16 + rA) * 32 + kq];
#pragma unroll
    for (int nt = 0; nt < 4; ++nt)
      b[nt] = *(const short8*)&Bs[(nt * 16 + rA) * 32 + kq];
#pragma unroll
    for (int mt = 0; mt < 4; ++mt)
#pragma unroll
      for (int nt = 0; nt < 4; ++nt)
        acc[mt][nt] = __builtin_amdgcn_mfma_f32_16x16x32_bf16(
            a[mt], b[nt], acc[mt][nt], 0, 0, 0);
    __syncthreads();
  }

  const int cq = lane >> 4;
  const int cn = lane & 15;
  float bi[4];
#pragma unroll
  for (int nt = 0; nt < 4; ++nt) bi[nt] = bias[n0 + nt * 16 + cn];

#pragma unroll
  for (int mt = 0; mt < 4; ++mt) {
#pragma unroll
    for (int r = 0; r < 4; ++r) {
      int m = m0 + wave * 64 + mt * 16 + cq * 4 + r;
      size_t rowoff = 0;
      if (MODE == 1) {
        int w = m / 49, rr = m - w * 49;
        int b = w >> 6, wrem = w & 63;
        int hi = wrem >> 3, wi = wrem & 7;
        int ii = rr / 7, jj = rr - ii * 7;
        int hd = hi * 7 + ii + 3; if (hd >= 56) hd -= 56;
        int wd = wi * 7 + jj + 3; if (wd >= 56) wd -= 56;
        rowoff = (size_t)((b * 56 + hd) * 56 + wd) * CC;
      }
#pragma unroll
      for (int nt = 0; nt < 4; ++nt) {
        int n = n0 + nt * 16 + cn;
        float v = acc[mt][nt][r] + bi[nt];
        if (MODE == 0) {
          ((bf16*)out0)[(size_t)m * N + n] = __float2bfloat16(v);
        } else if (MODE == 2) {
          float ge = 0.5f * v * (1.0f + erff(v * 0.70710678118654752f));
          ((bf16*)out0)[(size_t)m * N + n] = __float2bfloat16(ge);
        } else if (MODE == 1) {
          float res = ((const float*)aux)[rowoff + n];
          ((float*)out0)[rowoff + n] = v + res;
        } else {
          float res = ((const float*)aux)[(size_t)m * CC + n];
          ((float*)out0)[(size_t)m * CC + n] = v + res;
        }
      }
    }
  }
}

// ---------------- MFMA attention: 1 wave per (window,head) ---------------
// qkv: [M,576] row-major; q cols [0,192), k [192,384), v [384,576)
__global__ __launch_bounds__(256) void k_attn_mfma(
    const bf16* __restrict__ qk, const float* __restrict__ bias6,
    bf16* __restrict__ ao) {
  __shared__ bf16 P[4][64 * 72];   // per-wave P,  36,864 B total
  __shared__ bf16 VT[4][32 * 72];  // per-wave V^T, 18,432 B total
  const int wave = threadIdx.x >> 6, lane = threadIdx.x & 63;
  const int wh = blockIdx.x * 4 + wave;
  const int w = wh / NHEADS, h = wh - w * NHEADS;
  const int rA = lane & 15, kq = (lane >> 4) * 8;
  const int grp = lane >> 4;

  const bf16* qbase = qk + (size_t)(w * 49) * 576 + h * HDIM + kq;

  // ---- load Q,K fragments + V rows straight from global ----
  short8 aq[4], bk[4], vrow[4];
#pragma unroll
  for (int t = 0; t < 4; ++t) {
    const bf16* rp = qbase + (size_t)(t * 16 + rA) * 576;
    aq[t] = *(const short8*)(rp);
    bk[t] = *(const short8*)(rp + 192);
    vrow[t] = *(const short8*)(rp + 384);
  }

  // ---- QK^T ----
  f32x4 S[4][4] = {};
#pragma unroll
  for (int mt = 0; mt < 4; ++mt)
#pragma unroll
    for (int nt = 0; nt < 4; ++nt)
      S[mt][nt] = __builtin_amdgcn_mfma_f32_16x16x32_bf16(
          aq[mt], bk[nt], S[mt][nt], 0, 0, 0);

  // ---- V transpose into LDS: VT[d][tok64], zero pad tok>=49 ----
  bf16* Vw = VT[wave];
  const bf16 zero = __float2bfloat16(0.0f);
#pragma unroll
  for (int t = 0; t < 4; ++t) {
    int tok = t * 16 + rA;
#pragma unroll
    for (int j = 0; j < 8; ++j)
      Vw[(kq + j) * 72 + tok] = (tok < 49) ? ((const bf16*)&vrow[t])[j] : zero;
  }

  // ---- softmax over rows (row in one 16-lane group + 4 nt regs) ----
  const float scale = 0.17677669529663687f;
  const float* bh = bias6 + h * 2401;
  float rs[4][4];
  bf16* Pw = P[wave];
#pragma unroll
  for (int mt = 0; mt < 4; ++mt) {
#pragma unroll
    for (int r = 0; r < 4; ++r) {
      int row = mt * 16 + grp * 4 + r;
      float val[4];
#pragma unroll
      for (int nt = 0; nt < 4; ++nt) {
        int c = nt * 16 + rA;
        float bv = (row < 49 && c < 49) ? bh[row * 49 + c] : 0.0f;
        val[nt] = (c < 49) ? (S[mt][nt][r] * scale + bv) : -1e30f;
      }
      float mx = fmaxf(fmaxf(val[0], val[1]), fmaxf(val[2], val[3]));
      for (int m2 = 1; m2 < 16; m2 <<= 1) mx = fmaxf(mx, __shfl_xor(mx, m2, 64));
      float sum = 0.0f;
#pragma unroll
      for (int nt = 0; nt < 4; ++nt) {
        float e = __expf(val[nt] - mx);
        val[nt] = e;
        sum += e;
      }
      for (int m2 = 1; m2 < 16; m2 <<= 1) sum += __shfl_xor(sum, m2, 64);
      rs[mt][r] = 1.0f / sum;
#pragma unroll
      for (int nt = 0; nt < 4; ++nt)
        Pw[row * 72 + nt * 16 + rA] = __float2bfloat16(val[nt]);
    }
  }
  __syncthreads();

  // ---- PV: A-frags from P-LDS, B-frags (V^T) from VT-LDS ----
  short8 bv[2][2];
#pragma unroll
  for (int ks = 0; ks < 2; ++ks)
#pragma unroll
    for (int nt = 0; nt < 2; ++nt)
      bv[ks][nt] = *(const short8*)&Vw[(nt * 16 + rA) * 72 + ks * 32 + kq];
  f32x4 O[4][2] = {};
#pragma unroll
  for (int mt = 0; mt < 4; ++mt) {
    short8 ap0 = *(const short8*)&Pw[(mt * 16 + rA) * 72 + kq];
    short8 ap1 = *(const short8*)&Pw[(mt * 16 + rA) * 72 + 32 + kq];
#pragma unroll
    for (int nt = 0; nt < 2; ++nt) {
      O[mt][nt] = __builtin_amdgcn_mfma_f32_16x16x32_bf16(ap0, bv[0][nt],
                                                          O[mt][nt], 0, 0, 0);
      O[mt][nt] = __builtin_amdgcn_mfma_f32_16x16x32_bf16(ap1, bv[1][nt],
                                                          O[mt][nt], 0, 0, 0);
    }
  }
  // ---- write O (rows m<49), normalized by row sums ----
#pragma unroll
  for (int mt = 0; mt < 4; ++mt) {
#pragma unroll
    for (int r = 0; r < 4; ++r) {
      int m = mt * 16 + grp * 4 + r;
      if (m < 49) {
        bf16* orow = ao + (size_t)(w * 49 + m) * CC + h * HDIM;
#pragma unroll
        for (int nt = 0; nt < 2; ++nt)
          orow[nt * 16 + rA] = __float2bfloat16(O[mt][nt][r] * rs[mt][r]);
      }
    }
  }
}

// ---------------- launcher ----------------
extern "C" void kernel_launch(void* const* d_in, const int* in_sizes, int n_in,
                              void* d_out, int out_size, void* d_ws, size_t ws_size,
                              hipStream_t stream) {
  const float* x        = (const float*)d_in[0];
  const float* norm1_g  = (const float*)d_in[1];
  const float* norm1_b  = (const float*)d_in[2];
  const float* qkv_w    = (const float*)d_in[3];
  const float* qkv_b    = (const float*)d_in[4];
  const float* proj_w   = (const float*)d_in[5];
  const float* proj_b   = (const float*)d_in[6];
  const float* rel_tab  = (const float*)d_in[7];
  const float* norm2_g  = (const float*)d_in[8];
  const float* norm2_b  = (const float*)d_in[9];
  const float* fc1_w    = (const float*)d_in[10];
  const float* fc1_b    = (const float*)d_in[11];
  const float* fc2_w    = (const float*)d_in[12];
  const float* fc2_b    = (const float*)d_in[13];
  const int*   rel_idx  = (const int*)d_in[14];
  float* out = (float*)d_out;

  // workspace layout (bytes):
  //   [0,           38,535,168)   slotA: xw -> ao -> xn2       (bf16 M*192)
  //   [38,535,168, 154,140,672)   qkv [M,576] bf16 (115,605,504 B; later hbuf)
  //   [154,140,672,155,025,408)   wbuf bf16 weights (884,736 B)
  //   [155,025,408,155,083,032)   bias6 fp32 (57,624 B)
  char* ws = (char*)d_ws;
  bf16*  xw    = (bf16*)ws;
  bf16*  qkb   = (bf16*)(ws + 38535168);
  bf16*  wbuf  = (bf16*)(ws + 154140672);
  float* bias6 = (float*)(ws + 155025408);
  bf16*  ao    = xw;
  bf16*  xn2   = xw;
  bf16*  hbuf  = qkb;   // 77,070,336 B needed, 115.6 MB available
  float* x1    = out;   // fp32 residual trunk lives in d_out
  bf16* wq = wbuf;
  bf16* wp = wbuf + 110592;
  bf16* w1 = wbuf + 147456;
  bf16* w2 = wbuf + 294912;

  k_wconv<<<1728, 256, 0, stream>>>(qkv_w, proj_w, fc1_w, fc2_w, wbuf);
  k_bias<<<57, 256, 0, stream>>>(rel_tab, rel_idx, bias6);
  k_ln1_part<<<MTOK / 4, 256, 0, stream>>>(x, norm1_g, norm1_b, xw);
  // qkv: [M,192] @ [576,192]^T -> [M,576] row-major
  k_mgemm<0><<<dim3(576 / 64, MTOK / 256), 256, 0, stream>>>(
      xw, wq, qkv_b, qkb, nullptr, 192, 576);
  k_attn_mfma<<<NWIN * NHEADS / 4, 256, 0, stream>>>(qkb, bias6, ao);
  // proj + reverse/roll + residual -> x1 (d_out, fp32 natural order)
  k_mgemm<1><<<dim3(192 / 64, MTOK / 256), 256, 0, stream>>>(
      ao, wp, proj_b, x1, x, 192, 192);
  k_ln2<<<MTOK / 4, 256, 0, stream>>>(x1, norm2_g, norm2_b, xn2);
  const int MH = MTOK / 2;  // 50176
  for (int h = 0; h < 2; ++h) {
    size_t mo = (size_t)h * MH;
    k_mgemm<2><<<dim3(HIDDEN / 64, MH / 256), 256, 0, stream>>>(
        xn2 + mo * CC, w1, fc1_b, hbuf, nullptr, 192, 768);
    k_mgemm<3><<<dim3(CC / 64, MH / 256), 256, 0, stream>>>(
        hbuf, w2, fc2_b, out + mo * CC, x1 + mo * CC, 768, 192);
  }
}